// Round 3
// baseline (826.384 us; speedup 1.0000x reference)
//
#include <hip/hip_runtime.h>
#include <cstddef>
#include <cstdint>

__device__ __forceinline__ float lrelu_f(float v) { return v > 0.f ? v : 0.2f * v; }

// ---------------- prep: pad x [B,N,6] -> [B,N,16], compute xx ----------------
__global__ void prepx_kernel(const float* __restrict__ x, float* __restrict__ xpad,
                             float* __restrict__ xx) {
  int p = blockIdx.x * 256 + threadIdx.x;  // 0..16383
  const float* xp = x + (size_t)p * 6;
  float v[6];
  float s = 0.f;
#pragma unroll
  for (int c = 0; c < 6; ++c) { v[c] = xp[c]; s = fmaf(v[c], v[c], s); }
  float* o = xpad + (size_t)p * 16;
#pragma unroll
  for (int c = 0; c < 6; ++c) o[c] = v[c];
#pragma unroll
  for (int c = 6; c < 16; ++c) o[c] = 0.f;
  xx[p] = s;
}

// ---------------- Wc prep: [2out, dpad]; rows 0..out-1 = W_a, out.. = W_b - W_a
__global__ void wcprep_kernel(const float* __restrict__ W, float* __restrict__ Wc,
                              int out, int d, int dpad) {
  int i = blockIdx.x * 256 + threadIdx.x;
  if (i >= 2 * out * dpad) return;
  int j = i / dpad, c = i - j * dpad;
  float v = 0.f;
  if (c < d) {
    v = (j < out) ? W[j * 2 * d + c]
                  : (W[(j - out) * 2 * d + d + c] - W[(j - out) * 2 * d + c]);
  }
  Wc[i] = v;
}

// ---------------- pairwise "distance" matrix D[b,i,j] = 2*dot - xx_i - xx_j ---
__global__ __launch_bounds__(256) void dist_kernel(
    const float* __restrict__ F, const float* __restrict__ xx,
    float* __restrict__ D, int stride, int off, int dpad) {
  int b = blockIdx.z;
  int rowbase = blockIdx.y * 64, colbase = blockIdx.x * 64;
  const float* Fb = F + (size_t)b * 1024 * stride + off;
  const float* xxb = xx + b * 1024;
  __shared__ __align__(16) float As[16][68];
  __shared__ __align__(16) float Bs[16][68];
  int tid = threadIdx.x;
  int tx = tid & 15, ty = tid >> 4;
  int lp = tid >> 2, lk = (tid & 3) * 4;
  float acc[4][4] = {};
  for (int k0 = 0; k0 < dpad; k0 += 16) {
    float4 av = *(const float4*)(Fb + (size_t)(rowbase + lp) * stride + k0 + lk);
    float4 bv = *(const float4*)(Fb + (size_t)(colbase + lp) * stride + k0 + lk);
    __syncthreads();
    As[lk + 0][lp] = av.x; As[lk + 1][lp] = av.y; As[lk + 2][lp] = av.z; As[lk + 3][lp] = av.w;
    Bs[lk + 0][lp] = bv.x; Bs[lk + 1][lp] = bv.y; Bs[lk + 2][lp] = bv.z; Bs[lk + 3][lp] = bv.w;
    __syncthreads();
#pragma unroll
    for (int kk = 0; kk < 16; ++kk) {
      float4 a4 = *(const float4*)&As[kk][ty * 4];
      float4 b4 = *(const float4*)&Bs[kk][tx * 4];
      float ar[4] = {a4.x, a4.y, a4.z, a4.w};
      float br[4] = {b4.x, b4.y, b4.z, b4.w};
#pragma unroll
      for (int i = 0; i < 4; ++i)
#pragma unroll
        for (int j = 0; j < 4; ++j) acc[i][j] = fmaf(ar[i], br[j], acc[i][j]);
    }
  }
  float xc[4];
#pragma unroll
  for (int j = 0; j < 4; ++j) xc[j] = xxb[colbase + tx * 4 + j];
  size_t Dbase = ((size_t)b << 20);
#pragma unroll
  for (int i = 0; i < 4; ++i) {
    int r = rowbase + ty * 4 + i;
    float xr = xxb[r];
    float4 o;
    o.x = 2.f * acc[i][0] - xr - xc[0];
    o.y = 2.f * acc[i][1] - xr - xc[1];
    o.z = 2.f * acc[i][2] - xr - xc[2];
    o.w = 2.f * acc[i][3] - xr - xc[3];
    *(float4*)(D + Dbase + (size_t)r * 1024 + colbase + tx * 4) = o;
  }
}

// ---- top-20 per row: ballot radix bit-descent (exact, tie=lower index) ------
// Wave per row. Keys: fp32 -> order-preserving u32. Zero cross-lane DS ops.
__global__ __launch_bounds__(256) void topk_kernel(const float* __restrict__ D,
                                                   int* __restrict__ idx) {
  int wv = threadIdx.x >> 6, lane = threadIdx.x & 63;
  int row = blockIdx.x * 4 + wv;  // 0..16383 (batch*1024 + n)
  const float* Dr = D + (size_t)row * 1024;
  unsigned u[16];
#pragma unroll
  for (int j = 0; j < 16; ++j) {
    unsigned bits = __float_as_uint(Dr[j * 64 + lane]);
    unsigned m = (unsigned)((int)bits >> 31);
    u[j] = bits ^ (m | 0x80000000u);  // order-preserving map
  }
  // find T = 20th-largest key: max X with count(u >= X) >= 20
  unsigned X = 0;
  for (int b = 31; b >= 0; --b) {
    unsigned Xt = X | (1u << b);
    int c = 0;
#pragma unroll
    for (int j = 0; j < 16; ++j) c += __popcll(__ballot(u[j] >= Xt));
    if (c >= 20) X = Xt;
  }
  const unsigned T = X;
  unsigned long long lanebit = 1ull << lane;
  int* op = idx + (size_t)row * 20;
  // pass 1: strictly greater than T (count < 20 by construction)
  int base = 0;
#pragma unroll
  for (int j = 0; j < 16; ++j) {
    unsigned long long m = __ballot(u[j] > T);
    int before = __popcll(m & (lanebit - 1ull));
    if (m & lanebit) op[base + before] = j * 64 + lane;
    base += __popcll(m);
  }
  // pass 2: equal to T, ascending global index (j asc, lane asc), fill to 20
#pragma unroll
  for (int j = 0; j < 16; ++j) {
    unsigned long long m = __ballot(u[j] == T);
    int before = __popcll(m & (lanebit - 1ull));
    int pos = base + before;
    if ((m & lanebit) && pos < 20) op[pos] = j * 64 + lane;
    base += __popcll(m);
  }
}

// ---------------- AB = F @ Wc^T : [16384, 2out] --------------------------------
__global__ __launch_bounds__(256) void ab_kernel(
    const float* __restrict__ F, int stride, int off, int dpad,
    const float* __restrict__ Wc, int twoout, float* __restrict__ AB) {
  int pb = blockIdx.x * 64, cb = blockIdx.y * 64;
  __shared__ __align__(16) float As[16][68];
  __shared__ __align__(16) float Bs[16][68];
  int tid = threadIdx.x;
  int tx = tid & 15, ty = tid >> 4;
  int lp = tid >> 2, lk = (tid & 3) * 4;
  float acc[4][4] = {};
  for (int k0 = 0; k0 < dpad; k0 += 16) {
    float4 av = *(const float4*)(F + (size_t)(pb + lp) * stride + off + k0 + lk);
    float4 bv = *(const float4*)(Wc + (size_t)(cb + lp) * dpad + k0 + lk);
    __syncthreads();
    As[lk + 0][lp] = av.x; As[lk + 1][lp] = av.y; As[lk + 2][lp] = av.z; As[lk + 3][lp] = av.w;
    Bs[lk + 0][lp] = bv.x; Bs[lk + 1][lp] = bv.y; Bs[lk + 2][lp] = bv.z; Bs[lk + 3][lp] = bv.w;
    __syncthreads();
#pragma unroll
    for (int kk = 0; kk < 16; ++kk) {
      float4 a4 = *(const float4*)&As[kk][ty * 4];
      float4 b4 = *(const float4*)&Bs[kk][tx * 4];
      float ar[4] = {a4.x, a4.y, a4.z, a4.w};
      float br[4] = {b4.x, b4.y, b4.z, b4.w};
#pragma unroll
      for (int i = 0; i < 4; ++i)
#pragma unroll
        for (int j = 0; j < 4; ++j) acc[i][j] = fmaf(ar[i], br[j], acc[i][j]);
    }
  }
#pragma unroll
  for (int i = 0; i < 4; ++i) {
    float4 o = {acc[i][0], acc[i][1], acc[i][2], acc[i][3]};
    *(float4*)(AB + (size_t)(pb + ty * 4 + i) * twoout + cb + tx * 4) = o;
  }
}

// ------- out[p,o] = max_t lrelu(A[idx[p][t],o] + Bc[p,o]); optional xx -------
__global__ void gathermax_kernel(const float* __restrict__ AB, const int* __restrict__ idx,
                                 float* __restrict__ catb, float* __restrict__ xx,
                                 int out, int catoff, int needxx) {
  int tid = threadIdx.x;
  int q = tid / out, o = tid - q * out;
  int ppb = 256 / out;
  int p = blockIdx.x * ppb + q;  // global point 0..16383
  int twoout = out * 2;
  const int* ip = idx + (size_t)p * 20;
  float bias = AB[(size_t)p * twoout + out + o];
  int bbase = p & ~1023;
  float m = -3.402823466e38f;
#pragma unroll
  for (int t = 0; t < 20; ++t) {
    int j = ip[t];
    float v = AB[(size_t)(bbase + j) * twoout + o] + bias;
    v = v > 0.f ? v : 0.2f * v;
    m = fmaxf(m, v);
  }
  catb[(size_t)p * 512 + catoff + o] = m;
  if (needxx) {
    __shared__ float buf[256];
    buf[tid] = m * m;
    __syncthreads();
    for (int s = out >> 1; s > 0; s >>= 1) {
      if (o < s) buf[tid] += buf[tid + s];
      __syncthreads();
    }
    if (o == 0) xx[p] = buf[tid];
  }
}

// ------- partial[b,nb,o] = max over 64-point chunk of lrelu(W4 @ cat) ---------
__global__ __launch_bounds__(256) void gemmmax_kernel(
    const float* __restrict__ catb, const float* __restrict__ W4,
    float* __restrict__ partial) {
  int b = blockIdx.z;
  int ob = blockIdx.x * 64, nb = blockIdx.y * 64;
  __shared__ __align__(16) float As[16][68];
  __shared__ __align__(16) float Bs[16][68];
  int tid = threadIdx.x;
  int tx = tid & 15, ty = tid >> 4;
  int lp = tid >> 2, lk = (tid & 3) * 4;
  float acc[4][4] = {};
  for (int k0 = 0; k0 < 512; k0 += 16) {
    float4 av = *(const float4*)(W4 + (size_t)(ob + lp) * 512 + k0 + lk);
    float4 bv = *(const float4*)(catb + (size_t)(b * 1024 + nb + lp) * 512 + k0 + lk);
    __syncthreads();
    As[lk + 0][lp] = av.x; As[lk + 1][lp] = av.y; As[lk + 2][lp] = av.z; As[lk + 3][lp] = av.w;
    Bs[lk + 0][lp] = bv.x; Bs[lk + 1][lp] = bv.y; Bs[lk + 2][lp] = bv.z; Bs[lk + 3][lp] = bv.w;
    __syncthreads();
#pragma unroll
    for (int kk = 0; kk < 16; ++kk) {
      float4 a4 = *(const float4*)&As[kk][ty * 4];
      float4 b4 = *(const float4*)&Bs[kk][tx * 4];
      float ar[4] = {a4.x, a4.y, a4.z, a4.w};
      float br[4] = {b4.x, b4.y, b4.z, b4.w};
#pragma unroll
      for (int i = 0; i < 4; ++i)
#pragma unroll
        for (int j = 0; j < 4; ++j) acc[i][j] = fmaf(ar[i], br[j], acc[i][j]);
    }
  }
  __shared__ float red[64][17];
#pragma unroll
  for (int i = 0; i < 4; ++i) {
    float m = lrelu_f(acc[i][0]);
    m = fmaxf(m, lrelu_f(acc[i][1]));
    m = fmaxf(m, lrelu_f(acc[i][2]));
    m = fmaxf(m, lrelu_f(acc[i][3]));
    red[ty * 4 + i][tx] = m;
  }
  __syncthreads();
  if (tid < 64) {
    float m = red[tid][0];
#pragma unroll
    for (int t = 1; t < 16; ++t) m = fmaxf(m, red[tid][t]);
    partial[((size_t)(b * 16 + blockIdx.y) << 10) + ob + tid] = m;
  }
}

// ---------------- final: g = max over chunks; tiny MLP head -------------------
__global__ __launch_bounds__(256) void final_kernel(
    const float* __restrict__ partial, const float* __restrict__ y,
    const float* __restrict__ F0w, const float* __restrict__ F0b,
    const float* __restrict__ F1w, const float* __restrict__ F1b,
    const float* __restrict__ L0, const float* __restrict__ L1,
    const float* __restrict__ L2w, const float* __restrict__ L2b,
    float* __restrict__ outp) {
  int b = blockIdx.x, tid = threadIdx.x;
  __shared__ __align__(16) float z[1088];
  __shared__ __align__(16) float z1[512];
  __shared__ __align__(16) float z2[256];
  __shared__ float ye0[16];
  for (int o = tid; o < 1024; o += 256) {
    float m = -3.402823466e38f;
#pragma unroll
    for (int nb = 0; nb < 16; ++nb)
      m = fmaxf(m, partial[((size_t)(b * 16 + nb) << 10) + o]);
    z[o] = m;
  }
  if (tid < 16) {
    float s = F0b[tid];
#pragma unroll
    for (int c = 0; c < 16; ++c) s = fmaf(y[b * 16 + c], F0w[tid * 16 + c], s);
    ye0[tid] = lrelu_f(s);
  }
  __syncthreads();
  if (tid < 64) {
    float s = F1b[tid];
#pragma unroll
    for (int c = 0; c < 16; ++c) s = fmaf(ye0[c], F1w[tid * 16 + c], s);
    z[1024 + tid] = lrelu_f(s);
  }
  __syncthreads();
  for (int j = tid; j < 512; j += 256) {
    const float4* Lr = (const float4*)(L0 + (size_t)j * 1088);
    float s = 0.f;
#pragma unroll 4
    for (int c = 0; c < 272; ++c) {
      float4 w = Lr[c];
      float4 zz = *(const float4*)&z[c * 4];
      s = fmaf(w.x, zz.x, s); s = fmaf(w.y, zz.y, s);
      s = fmaf(w.z, zz.z, s); s = fmaf(w.w, zz.w, s);
    }
    z1[j] = lrelu_f(s);
  }
  __syncthreads();
  {
    const float4* Lr = (const float4*)(L1 + (size_t)tid * 512);
    float s = 0.f;
#pragma unroll 4
    for (int c = 0; c < 128; ++c) {
      float4 w = Lr[c];
      float4 zz = *(const float4*)&z1[c * 4];
      s = fmaf(w.x, zz.x, s); s = fmaf(w.y, zz.y, s);
      s = fmaf(w.z, zz.z, s); s = fmaf(w.w, zz.w, s);
    }
    z2[tid] = lrelu_f(s);
  }
  __syncthreads();
  float s = z2[tid] * L2w[tid];
#pragma unroll
  for (int m = 32; m >= 1; m >>= 1) s += __shfl_xor(s, m);
  __shared__ float wsum[4];
  if ((tid & 63) == 0) wsum[tid >> 6] = s;
  __syncthreads();
  if (tid == 0) outp[b] = wsum[0] + wsum[1] + wsum[2] + wsum[3] + L2b[0];
}

extern "C" void kernel_launch(void* const* d_in, const int* in_sizes, int n_in,
                              void* d_out, int out_size, void* d_ws, size_t ws_size,
                              hipStream_t stream) {
  const float* x = (const float*)d_in[0];
  const float* y = (const float*)d_in[1];
  const float* Wl[4] = {(const float*)d_in[2], (const float*)d_in[3],
                        (const float*)d_in[4], (const float*)d_in[5]};
  const float* W4 = (const float*)d_in[6];
  const float* L0 = (const float*)d_in[7];
  const float* L1 = (const float*)d_in[8];
  const float* L2w = (const float*)d_in[9];
  const float* L2b = (const float*)d_in[10];
  const float* F0w = (const float*)d_in[11];
  const float* F0b = (const float*)d_in[12];
  const float* F1w = (const float*)d_in[13];
  const float* F1b = (const float*)d_in[14];

  float* ws = (float*)d_ws;
  float* xpad = ws;                     // 16384*16      = 262144
  float* catb = ws + 262144;            // 16384*512     = 8388608
  float* D    = ws + 8650752;           // 16*1024*1024  = 16777216
  float* AB   = ws + 25427968;          // 16384*512     = 8388608
  int*   idx  = (int*)(ws + 33816576);  // 16384*20      = 327680
  float* xx   = ws + 34144256;          // 16384
  float* Wc   = ws + 34160640;          // 512*128       = 65536
  float* part = ws + 34226176;          // 16*16*1024    = 262144

  prepx_kernel<<<64, 256, 0, stream>>>(x, xpad, xx);

  struct LC { const float* F; int stride, off, d, dpad, out, catoff, needxx; };
  LC lc[4] = {
      {xpad, 16, 0, 6, 16, 64, 0, 1},
      {catb, 512, 0, 64, 64, 64, 64, 1},
      {catb, 512, 64, 64, 64, 128, 128, 1},
      {catb, 512, 128, 128, 128, 256, 256, 0},
  };
  for (int l = 0; l < 4; ++l) {
    LC c = lc[l];
    int twoout = c.out * 2;
    wcprep_kernel<<<(2 * c.out * c.dpad + 255) / 256, 256, 0, stream>>>(
        Wl[l], Wc, c.out, c.d, c.dpad);
    dist_kernel<<<dim3(16, 16, 16), 256, 0, stream>>>(c.F, xx, D, c.stride, c.off, c.dpad);
    topk_kernel<<<4096, 256, 0, stream>>>(D, idx);
    ab_kernel<<<dim3(256, twoout / 64), 256, 0, stream>>>(
        c.F, c.stride, c.off, c.dpad, Wc, twoout, AB);
    gathermax_kernel<<<16384 * c.out / 256, 256, 0, stream>>>(
        AB, idx, catb, xx, c.out, c.catoff, c.needxx);
  }
  gemmmax_kernel<<<dim3(16, 16, 16), 256, 0, stream>>>(catb, W4, part);
  final_kernel<<<16, 256, 0, stream>>>(part, y, F0w, F0b, F1w, F1b, L0, L1, L2w, L2b,
                                       (float*)d_out);
}

// Round 4
// 679.097 us; speedup vs baseline: 1.2169x; 1.2169x over previous
//
#include <hip/hip_runtime.h>
#include <cstddef>
#include <cstdint>

typedef __attribute__((ext_vector_type(8))) short bf16x8;
typedef __attribute__((ext_vector_type(4))) float f32x4;

__device__ __forceinline__ float lrelu_f(float v) { return v > 0.f ? v : 0.2f * v; }

__device__ __forceinline__ unsigned short f2bf_rne(float f) {
  unsigned u = __float_as_uint(f);
  return (unsigned short)((u + 0x7fffu + ((u >> 16) & 1u)) >> 16);
}
__device__ __forceinline__ float bf2f(unsigned short h) {
  return __uint_as_float((unsigned)h << 16);
}

// ---------------- prep: pad x [B,N,6] -> [B,N,16], compute xx ----------------
__global__ void prepx_kernel(const float* __restrict__ x, float* __restrict__ xpad,
                             float* __restrict__ xx) {
  int p = blockIdx.x * 256 + threadIdx.x;  // 0..16383
  const float* xp = x + (size_t)p * 6;
  float v[6];
  float s = 0.f;
#pragma unroll
  for (int c = 0; c < 6; ++c) { v[c] = xp[c]; s = fmaf(v[c], v[c], s); }
  float* o = xpad + (size_t)p * 16;
#pragma unroll
  for (int c = 0; c < 6; ++c) o[c] = v[c];
#pragma unroll
  for (int c = 6; c < 16; ++c) o[c] = 0.f;
  xx[p] = s;
}

// ---------------- Wc prep: [2out, dpad]; rows 0..out-1 = W_a, out.. = W_b - W_a
__global__ void wcprep_kernel(const float* __restrict__ W, float* __restrict__ Wc,
                              int out, int d, int dpad) {
  int i = blockIdx.x * 256 + threadIdx.x;
  if (i >= 2 * out * dpad) return;
  int j = i / dpad, c = i - j * dpad;
  float v = 0.f;
  if (c < d) {
    v = (j < out) ? W[j * 2 * d + c]
                  : (W[(j - out) * 2 * d + d + c] - W[(j - out) * 2 * d + c]);
  }
  Wc[i] = v;
}

// ---------------- W4 -> bf16 hi/lo split ------------------------------------
__global__ void w4prep_kernel(const float* __restrict__ W4,
                              unsigned short* __restrict__ W4h,
                              unsigned short* __restrict__ W4l) {
  int i = blockIdx.x * 256 + threadIdx.x;  // 0..524287
  float v = W4[i];
  unsigned short h = f2bf_rne(v);
  W4h[i] = h;
  W4l[i] = f2bf_rne(v - bf2f(h));
}

// ---------------- pairwise "distance" matrix D[b,i,j] = 2*dot - xx_i - xx_j ---
__global__ __launch_bounds__(256) void dist_kernel(
    const float* __restrict__ F, const float* __restrict__ xx,
    float* __restrict__ D, int stride, int off, int dpad) {
  int b = blockIdx.z;
  int rowbase = blockIdx.y * 64, colbase = blockIdx.x * 64;
  const float* Fb = F + (size_t)b * 1024 * stride + off;
  const float* xxb = xx + b * 1024;
  __shared__ __align__(16) float As[16][68];
  __shared__ __align__(16) float Bs[16][68];
  int tid = threadIdx.x;
  int tx = tid & 15, ty = tid >> 4;
  int lp = tid >> 2, lk = (tid & 3) * 4;
  float acc[4][4] = {};
  for (int k0 = 0; k0 < dpad; k0 += 16) {
    float4 av = *(const float4*)(Fb + (size_t)(rowbase + lp) * stride + k0 + lk);
    float4 bv = *(const float4*)(Fb + (size_t)(colbase + lp) * stride + k0 + lk);
    __syncthreads();
    As[lk + 0][lp] = av.x; As[lk + 1][lp] = av.y; As[lk + 2][lp] = av.z; As[lk + 3][lp] = av.w;
    Bs[lk + 0][lp] = bv.x; Bs[lk + 1][lp] = bv.y; Bs[lk + 2][lp] = bv.z; Bs[lk + 3][lp] = bv.w;
    __syncthreads();
#pragma unroll
    for (int kk = 0; kk < 16; ++kk) {
      float4 a4 = *(const float4*)&As[kk][ty * 4];
      float4 b4 = *(const float4*)&Bs[kk][tx * 4];
      float ar[4] = {a4.x, a4.y, a4.z, a4.w};
      float br[4] = {b4.x, b4.y, b4.z, b4.w};
#pragma unroll
      for (int i = 0; i < 4; ++i)
#pragma unroll
        for (int j = 0; j < 4; ++j) acc[i][j] = fmaf(ar[i], br[j], acc[i][j]);
    }
  }
  float xc[4];
#pragma unroll
  for (int j = 0; j < 4; ++j) xc[j] = xxb[colbase + tx * 4 + j];
  size_t Dbase = ((size_t)b << 20);
#pragma unroll
  for (int i = 0; i < 4; ++i) {
    int r = rowbase + ty * 4 + i;
    float xr = xxb[r];
    float4 o;
    o.x = 2.f * acc[i][0] - xr - xc[0];
    o.y = 2.f * acc[i][1] - xr - xc[1];
    o.z = 2.f * acc[i][2] - xr - xc[2];
    o.w = 2.f * acc[i][3] - xr - xc[3];
    *(float4*)(D + Dbase + (size_t)r * 1024 + colbase + tx * 4) = o;
  }
}

// ---- top-20 per row: ballot radix bit-descent (exact, tie=lower index) ------
__global__ __launch_bounds__(256) void topk_kernel(const float* __restrict__ D,
                                                   int* __restrict__ idx) {
  int wv = threadIdx.x >> 6, lane = threadIdx.x & 63;
  int row = blockIdx.x * 4 + wv;  // 0..16383 (batch*1024 + n)
  const float* Dr = D + (size_t)row * 1024;
  unsigned u[16];
#pragma unroll
  for (int j = 0; j < 16; ++j) {
    unsigned bits = __float_as_uint(Dr[j * 64 + lane]);
    unsigned m = (unsigned)((int)bits >> 31);
    u[j] = bits ^ (m | 0x80000000u);  // order-preserving map
  }
  unsigned X = 0;
  for (int b = 31; b >= 0; --b) {
    unsigned Xt = X | (1u << b);
    int c = 0;
#pragma unroll
    for (int j = 0; j < 16; ++j) c += __popcll(__ballot(u[j] >= Xt));
    if (c >= 20) X = Xt;
  }
  const unsigned T = X;
  unsigned long long lanebit = 1ull << lane;
  int* op = idx + (size_t)row * 20;
  int base = 0;
#pragma unroll
  for (int j = 0; j < 16; ++j) {
    unsigned long long m = __ballot(u[j] > T);
    int before = __popcll(m & (lanebit - 1ull));
    if (m & lanebit) op[base + before] = j * 64 + lane;
    base += __popcll(m);
  }
#pragma unroll
  for (int j = 0; j < 16; ++j) {
    unsigned long long m = __ballot(u[j] == T);
    int before = __popcll(m & (lanebit - 1ull));
    int pos = base + before;
    if ((m & lanebit) && pos < 20) op[pos] = j * 64 + lane;
    base += __popcll(m);
  }
}

// ---------------- AB = F @ Wc^T : [16384, 2out] --------------------------------
__global__ __launch_bounds__(256) void ab_kernel(
    const float* __restrict__ F, int stride, int off, int dpad,
    const float* __restrict__ Wc, int twoout, float* __restrict__ AB) {
  int pb = blockIdx.x * 64, cb = blockIdx.y * 64;
  __shared__ __align__(16) float As[16][68];
  __shared__ __align__(16) float Bs[16][68];
  int tid = threadIdx.x;
  int tx = tid & 15, ty = tid >> 4;
  int lp = tid >> 2, lk = (tid & 3) * 4;
  float acc[4][4] = {};
  for (int k0 = 0; k0 < dpad; k0 += 16) {
    float4 av = *(const float4*)(F + (size_t)(pb + lp) * stride + off + k0 + lk);
    float4 bv = *(const float4*)(Wc + (size_t)(cb + lp) * dpad + k0 + lk);
    __syncthreads();
    As[lk + 0][lp] = av.x; As[lk + 1][lp] = av.y; As[lk + 2][lp] = av.z; As[lk + 3][lp] = av.w;
    Bs[lk + 0][lp] = bv.x; Bs[lk + 1][lp] = bv.y; Bs[lk + 2][lp] = bv.z; Bs[lk + 3][lp] = bv.w;
    __syncthreads();
#pragma unroll
    for (int kk = 0; kk < 16; ++kk) {
      float4 a4 = *(const float4*)&As[kk][ty * 4];
      float4 b4 = *(const float4*)&Bs[kk][tx * 4];
      float ar[4] = {a4.x, a4.y, a4.z, a4.w};
      float br[4] = {b4.x, b4.y, b4.z, b4.w};
#pragma unroll
      for (int i = 0; i < 4; ++i)
#pragma unroll
        for (int j = 0; j < 4; ++j) acc[i][j] = fmaf(ar[i], br[j], acc[i][j]);
    }
  }
#pragma unroll
  for (int i = 0; i < 4; ++i) {
    float4 o = {acc[i][0], acc[i][1], acc[i][2], acc[i][3]};
    *(float4*)(AB + (size_t)(pb + ty * 4 + i) * twoout + cb + tx * 4) = o;
  }
}

// ------- out[p,o] = max_t lrelu(A[idx[p][t],o] + Bc[p,o]); bf16 hi/lo too ----
__global__ void gathermax_kernel(const float* __restrict__ AB, const int* __restrict__ idx,
                                 float* __restrict__ catb,
                                 unsigned short* __restrict__ cat_hi,
                                 unsigned short* __restrict__ cat_lo,
                                 float* __restrict__ xx,
                                 int out, int catoff, int needxx) {
  int tid = threadIdx.x;
  int q = tid / out, o = tid - q * out;
  int ppb = 256 / out;
  int p = blockIdx.x * ppb + q;  // global point 0..16383
  int twoout = out * 2;
  const int* ip = idx + (size_t)p * 20;
  float bias = AB[(size_t)p * twoout + out + o];
  int bbase = p & ~1023;
  float m = -3.402823466e38f;
#pragma unroll
  for (int t = 0; t < 20; ++t) {
    int j = ip[t];
    float v = AB[(size_t)(bbase + j) * twoout + o] + bias;
    v = v > 0.f ? v : 0.2f * v;
    m = fmaxf(m, v);
  }
  size_t ci = (size_t)p * 512 + catoff + o;
  catb[ci] = m;
  unsigned short h = f2bf_rne(m);
  cat_hi[ci] = h;
  cat_lo[ci] = f2bf_rne(m - bf2f(h));
  if (needxx) {
    __shared__ float buf[256];
    buf[tid] = m * m;
    __syncthreads();
    for (int s = out >> 1; s > 0; s >>= 1) {
      if (o < s) buf[tid] += buf[tid + s];
      __syncthreads();
    }
    if (o == 0) xx[p] = buf[tid];
  }
}

// ------- partial[b,nb,o] = max over 64-pt chunk of lrelu(W4 @ cat), bf16x3 MFMA
// Block: 256 thr = 4 waves; tile M=128 (o) x N=64 (n); K=512, BK=32.
// 3-pass split: C = Ah*Bh + Ah*Bl + Al*Bh  (~17 mantissa bits).
__global__ __launch_bounds__(256) void gemmmax_kernel(
    const unsigned short* __restrict__ cat_hi, const unsigned short* __restrict__ cat_lo,
    const unsigned short* __restrict__ W4h, const unsigned short* __restrict__ W4l,
    float* __restrict__ partial) {
  int b = blockIdx.z;
  int ob = blockIdx.x * 128;        // o-tile base
  int ny = blockIdx.y;              // n-chunk (64 points)
  int p0 = b * 1024 + ny * 64;      // global point base
  __shared__ __align__(16) unsigned short Ah[128 * 40];
  __shared__ __align__(16) unsigned short Al[128 * 40];
  __shared__ __align__(16) unsigned short Bh[64 * 40];
  __shared__ __align__(16) unsigned short Bl[64 * 40];
  int tid = threadIdx.x;
  int wave = tid >> 6, lane = tid & 63;
  int l15 = lane & 15, l4 = lane >> 4;

  // staging coords
  int arow = tid >> 1, ac0 = (tid & 1) * 2;       // A: 2 rows/thread-pair, 2 chunks each
  int brow = tid >> 2, bc = tid & 3;              // B: 4 chunks per row

  f32x4 acc[2][4] = {};

  for (int k0 = 0; k0 < 512; k0 += 32) {
    uint4 a0 = *(const uint4*)(W4h + (size_t)(ob + arow) * 512 + k0 + ac0 * 8);
    uint4 a1 = *(const uint4*)(W4h + (size_t)(ob + arow) * 512 + k0 + (ac0 + 1) * 8);
    uint4 al0 = *(const uint4*)(W4l + (size_t)(ob + arow) * 512 + k0 + ac0 * 8);
    uint4 al1 = *(const uint4*)(W4l + (size_t)(ob + arow) * 512 + k0 + (ac0 + 1) * 8);
    uint4 b0 = *(const uint4*)(cat_hi + (size_t)(p0 + brow) * 512 + k0 + bc * 8);
    uint4 bl0 = *(const uint4*)(cat_lo + (size_t)(p0 + brow) * 512 + k0 + bc * 8);
    __syncthreads();
    *(uint4*)(Ah + arow * 40 + ac0 * 8) = a0;
    *(uint4*)(Ah + arow * 40 + (ac0 + 1) * 8) = a1;
    *(uint4*)(Al + arow * 40 + ac0 * 8) = al0;
    *(uint4*)(Al + arow * 40 + (ac0 + 1) * 8) = al1;
    *(uint4*)(Bh + brow * 40 + bc * 8) = b0;
    *(uint4*)(Bl + brow * 40 + bc * 8) = bl0;
    __syncthreads();

    bf16x8 ah[2], alr[2], bh[4], blr[4];
#pragma unroll
    for (int m = 0; m < 2; ++m) {
      int r = wave * 32 + m * 16 + l15;
      ah[m] = *(const bf16x8*)(Ah + r * 40 + l4 * 8);
      alr[m] = *(const bf16x8*)(Al + r * 40 + l4 * 8);
    }
#pragma unroll
    for (int n = 0; n < 4; ++n) {
      int r = n * 16 + l15;
      bh[n] = *(const bf16x8*)(Bh + r * 40 + l4 * 8);
      blr[n] = *(const bf16x8*)(Bl + r * 40 + l4 * 8);
    }
#pragma unroll
    for (int m = 0; m < 2; ++m)
#pragma unroll
      for (int n = 0; n < 4; ++n) {
        acc[m][n] = __builtin_amdgcn_mfma_f32_16x16x32_bf16(ah[m], bh[n], acc[m][n], 0, 0, 0);
        acc[m][n] = __builtin_amdgcn_mfma_f32_16x16x32_bf16(ah[m], blr[n], acc[m][n], 0, 0, 0);
        acc[m][n] = __builtin_amdgcn_mfma_f32_16x16x32_bf16(alr[m], bh[n], acc[m][n], 0, 0, 0);
      }
  }

  // epilogue: lrelu, max over n (4 frags in-lane, then 16-lane group reduce)
#pragma unroll
  for (int m = 0; m < 2; ++m)
#pragma unroll
    for (int r = 0; r < 4; ++r) {
      float v = lrelu_f(acc[m][0][r]);
      v = fmaxf(v, lrelu_f(acc[m][1][r]));
      v = fmaxf(v, lrelu_f(acc[m][2][r]));
      v = fmaxf(v, lrelu_f(acc[m][3][r]));
      v = fmaxf(v, __shfl_xor(v, 1));
      v = fmaxf(v, __shfl_xor(v, 2));
      v = fmaxf(v, __shfl_xor(v, 4));
      v = fmaxf(v, __shfl_xor(v, 8));
      if (l15 == 0)
        partial[((size_t)(b * 16 + ny) << 10) + ob + wave * 32 + m * 16 + l4 * 4 + r] = v;
    }
}

// ---------------- final: g = max over chunks; tiny MLP head -------------------
__global__ __launch_bounds__(256) void final_kernel(
    const float* __restrict__ partial, const float* __restrict__ y,
    const float* __restrict__ F0w, const float* __restrict__ F0b,
    const float* __restrict__ F1w, const float* __restrict__ F1b,
    const float* __restrict__ L0, const float* __restrict__ L1,
    const float* __restrict__ L2w, const float* __restrict__ L2b,
    float* __restrict__ outp) {
  int b = blockIdx.x, tid = threadIdx.x;
  __shared__ __align__(16) float z[1088];
  __shared__ __align__(16) float z1[512];
  __shared__ __align__(16) float z2[256];
  __shared__ float ye0[16];
  for (int o = tid; o < 1024; o += 256) {
    float m = -3.402823466e38f;
#pragma unroll
    for (int nb = 0; nb < 16; ++nb)
      m = fmaxf(m, partial[((size_t)(b * 16 + nb) << 10) + o]);
    z[o] = m;
  }
  if (tid < 16) {
    float s = F0b[tid];
#pragma unroll
    for (int c = 0; c < 16; ++c) s = fmaf(y[b * 16 + c], F0w[tid * 16 + c], s);
    ye0[tid] = lrelu_f(s);
  }
  __syncthreads();
  if (tid < 64) {
    float s = F1b[tid];
#pragma unroll
    for (int c = 0; c < 16; ++c) s = fmaf(ye0[c], F1w[tid * 16 + c], s);
    z[1024 + tid] = lrelu_f(s);
  }
  __syncthreads();
  for (int j = tid; j < 512; j += 256) {
    const float4* Lr = (const float4*)(L0 + (size_t)j * 1088);
    float s = 0.f;
#pragma unroll 4
    for (int c = 0; c < 272; ++c) {
      float4 w = Lr[c];
      float4 zz = *(const float4*)&z[c * 4];
      s = fmaf(w.x, zz.x, s); s = fmaf(w.y, zz.y, s);
      s = fmaf(w.z, zz.z, s); s = fmaf(w.w, zz.w, s);
    }
    z1[j] = lrelu_f(s);
  }
  __syncthreads();
  {
    const float4* Lr = (const float4*)(L1 + (size_t)tid * 512);
    float s = 0.f;
#pragma unroll 4
    for (int c = 0; c < 128; ++c) {
      float4 w = Lr[c];
      float4 zz = *(const float4*)&z1[c * 4];
      s = fmaf(w.x, zz.x, s); s = fmaf(w.y, zz.y, s);
      s = fmaf(w.z, zz.z, s); s = fmaf(w.w, zz.w, s);
    }
    z2[tid] = lrelu_f(s);
  }
  __syncthreads();
  float s = z2[tid] * L2w[tid];
#pragma unroll
  for (int m = 32; m >= 1; m >>= 1) s += __shfl_xor(s, m);
  __shared__ float wsum[4];
  if ((tid & 63) == 0) wsum[tid >> 6] = s;
  __syncthreads();
  if (tid == 0) outp[b] = wsum[0] + wsum[1] + wsum[2] + wsum[3] + L2b[0];
}

extern "C" void kernel_launch(void* const* d_in, const int* in_sizes, int n_in,
                              void* d_out, int out_size, void* d_ws, size_t ws_size,
                              hipStream_t stream) {
  const float* x = (const float*)d_in[0];
  const float* y = (const float*)d_in[1];
  const float* Wl[4] = {(const float*)d_in[2], (const float*)d_in[3],
                        (const float*)d_in[4], (const float*)d_in[5]};
  const float* W4 = (const float*)d_in[6];
  const float* L0 = (const float*)d_in[7];
  const float* L1 = (const float*)d_in[8];
  const float* L2w = (const float*)d_in[9];
  const float* L2b = (const float*)d_in[10];
  const float* F0w = (const float*)d_in[11];
  const float* F0b = (const float*)d_in[12];
  const float* F1w = (const float*)d_in[13];
  const float* F1b = (const float*)d_in[14];

  float* ws = (float*)d_ws;
  float* xpad = ws;                     // 16384*16      = 262144
  float* catb = ws + 262144;            // 16384*512     = 8388608
  float* D    = ws + 8650752;           // 16*1024*1024  = 16777216
  float* AB   = ws + 25427968;          // 16384*512     = 8388608
  int*   idx  = (int*)(ws + 33816576);  // 16384*20      = 327680
  float* xx   = ws + 34144256;          // 16384
  float* Wc   = ws + 34160640;          // 512*128       = 65536
  float* part = ws + 34226176;          // 16*16*1024    = 262144
  unsigned short* cat_hi = (unsigned short*)(ws + 34488320);  // 16384*512 u16
  unsigned short* cat_lo = (unsigned short*)(ws + 38682624);  // 16384*512 u16
  unsigned short* W4h    = (unsigned short*)(ws + 42876928);  // 1024*512 u16
  unsigned short* W4l    = (unsigned short*)(ws + 43139072);  // 1024*512 u16

  prepx_kernel<<<64, 256, 0, stream>>>(x, xpad, xx);
  w4prep_kernel<<<2048, 256, 0, stream>>>(W4, W4h, W4l);

  struct LC { const float* F; int stride, off, d, dpad, out, catoff, needxx; };
  LC lc[4] = {
      {xpad, 16, 0, 6, 16, 64, 0, 1},
      {catb, 512, 0, 64, 64, 64, 64, 1},
      {catb, 512, 64, 64, 64, 128, 128, 1},
      {catb, 512, 128, 128, 128, 256, 256, 0},
  };
  for (int l = 0; l < 4; ++l) {
    LC c = lc[l];
    int twoout = c.out * 2;
    wcprep_kernel<<<(2 * c.out * c.dpad + 255) / 256, 256, 0, stream>>>(
        Wl[l], Wc, c.out, c.d, c.dpad);
    dist_kernel<<<dim3(16, 16, 16), 256, 0, stream>>>(c.F, xx, D, c.stride, c.off, c.dpad);
    topk_kernel<<<4096, 256, 0, stream>>>(D, idx);
    ab_kernel<<<dim3(256, twoout / 64), 256, 0, stream>>>(
        c.F, c.stride, c.off, c.dpad, Wc, twoout, AB);
    gathermax_kernel<<<16384 * c.out / 256, 256, 0, stream>>>(
        AB, idx, catb, cat_hi, cat_lo, xx, c.out, c.catoff, c.needxx);
  }
  gemmmax_kernel<<<dim3(8, 16, 16), 256, 0, stream>>>(cat_hi, cat_lo, W4h, W4l, part);
  final_kernel<<<16, 256, 0, stream>>>(part, y, F0w, F0b, F1w, F1b, L0, L1, L2w, L2b,
                                       (float*)d_out);
}

// Round 7
// 607.112 us; speedup vs baseline: 1.3612x; 1.1186x over previous
//
#include <hip/hip_runtime.h>
#include <cstddef>
#include <cstdint>

typedef __attribute__((ext_vector_type(8))) short bf16x8;
typedef __attribute__((ext_vector_type(4))) float f32x4;

__device__ __forceinline__ float lrelu_f(float v) { return v > 0.f ? v : 0.2f * v; }

__device__ __forceinline__ unsigned short f2bf_rne(float f) {
  unsigned u = __float_as_uint(f);
  return (unsigned short)((u + 0x7fffu + ((u >> 16) & 1u)) >> 16);
}
__device__ __forceinline__ float bf2f(unsigned short h) {
  return __uint_as_float((unsigned)h << 16);
}

// ---------------- prep: pad x [B,N,6] -> [B,N,16], compute xx ----------------
__global__ void prepx_kernel(const float* __restrict__ x, float* __restrict__ xpad,
                             float* __restrict__ xx) {
  int p = blockIdx.x * 256 + threadIdx.x;  // 0..16383
  const float* xp = x + (size_t)p * 6;
  float v[6];
  float s = 0.f;
#pragma unroll
  for (int c = 0; c < 6; ++c) { v[c] = xp[c]; s = fmaf(v[c], v[c], s); }
  float* o = xpad + (size_t)p * 16;
#pragma unroll
  for (int c = 0; c < 6; ++c) o[c] = v[c];
#pragma unroll
  for (int c = 6; c < 16; ++c) o[c] = 0.f;
  xx[p] = s;
}

// ---------------- Wc prep: [2out, dpad]; rows 0..out-1 = W_a, out.. = W_b - W_a
__global__ void wcprep_kernel(const float* __restrict__ W, float* __restrict__ Wc,
                              int out, int d, int dpad) {
  int i = blockIdx.x * 256 + threadIdx.x;
  if (i >= 2 * out * dpad) return;
  int j = i / dpad, c = i - j * dpad;
  float v = 0.f;
  if (c < d) {
    v = (j < out) ? W[j * 2 * d + c]
                  : (W[(j - out) * 2 * d + d + c] - W[(j - out) * 2 * d + c]);
  }
  Wc[i] = v;
}

// ---------------- W4 -> bf16 hi/lo split ------------------------------------
__global__ void w4prep_kernel(const float* __restrict__ W4,
                              unsigned short* __restrict__ W4h,
                              unsigned short* __restrict__ W4l) {
  int i = blockIdx.x * 256 + threadIdx.x;  // 0..524287
  float v = W4[i];
  unsigned short h = f2bf_rne(v);
  W4h[i] = h;
  W4l[i] = f2bf_rne(v - bf2f(h));
}

// ---------------- pairwise "distance" matrix D[b,i,j] = 2*dot - xx_i - xx_j ---
__global__ __launch_bounds__(256) void dist_kernel(
    const float* __restrict__ F, const float* __restrict__ xx,
    float* __restrict__ D, int stride, int off, int dpad) {
  int b = blockIdx.z;
  int rowbase = blockIdx.y * 64, colbase = blockIdx.x * 64;
  const float* Fb = F + (size_t)b * 1024 * stride + off;
  const float* xxb = xx + b * 1024;
  __shared__ __align__(16) float As[16][68];
  __shared__ __align__(16) float Bs[16][68];
  int tid = threadIdx.x;
  int tx = tid & 15, ty = tid >> 4;
  int lp = tid >> 2, lk = (tid & 3) * 4;
  float acc[4][4] = {};
  for (int k0 = 0; k0 < dpad; k0 += 16) {
    float4 av = *(const float4*)(Fb + (size_t)(rowbase + lp) * stride + k0 + lk);
    float4 bv = *(const float4*)(Fb + (size_t)(colbase + lp) * stride + k0 + lk);
    __syncthreads();
    As[lk + 0][lp] = av.x; As[lk + 1][lp] = av.y; As[lk + 2][lp] = av.z; As[lk + 3][lp] = av.w;
    Bs[lk + 0][lp] = bv.x; Bs[lk + 1][lp] = bv.y; Bs[lk + 2][lp] = bv.z; Bs[lk + 3][lp] = bv.w;
    __syncthreads();
#pragma unroll
    for (int kk = 0; kk < 16; ++kk) {
      float4 a4 = *(const float4*)&As[kk][ty * 4];
      float4 b4 = *(const float4*)&Bs[kk][tx * 4];
      float ar[4] = {a4.x, a4.y, a4.z, a4.w};
      float br[4] = {b4.x, b4.y, b4.z, b4.w};
#pragma unroll
      for (int i = 0; i < 4; ++i)
#pragma unroll
        for (int j = 0; j < 4; ++j) acc[i][j] = fmaf(ar[i], br[j], acc[i][j]);
    }
  }
  float xc[4];
#pragma unroll
  for (int j = 0; j < 4; ++j) xc[j] = xxb[colbase + tx * 4 + j];
  size_t Dbase = ((size_t)b << 20);
#pragma unroll
  for (int i = 0; i < 4; ++i) {
    int r = rowbase + ty * 4 + i;
    float xr = xxb[r];
    float4 o;
    o.x = 2.f * acc[i][0] - xr - xc[0];
    o.y = 2.f * acc[i][1] - xr - xc[1];
    o.z = 2.f * acc[i][2] - xr - xc[2];
    o.w = 2.f * acc[i][3] - xr - xc[3];
    *(float4*)(D + Dbase + (size_t)r * 1024 + colbase + tx * 4) = o;
  }
}

// ---- top-20 per row: ballot radix bit-descent (exact, tie=lower index) ------
__global__ __launch_bounds__(256) void topk_kernel(const float* __restrict__ D,
                                                   int* __restrict__ idx) {
  int wv = threadIdx.x >> 6, lane = threadIdx.x & 63;
  int row = blockIdx.x * 4 + wv;  // 0..16383 (batch*1024 + n)
  const float* Dr = D + (size_t)row * 1024;
  unsigned u[16];
#pragma unroll
  for (int j = 0; j < 16; ++j) {
    unsigned bits = __float_as_uint(Dr[j * 64 + lane]);
    unsigned m = (unsigned)((int)bits >> 31);
    u[j] = bits ^ (m | 0x80000000u);  // order-preserving map
  }
  unsigned X = 0;
  for (int b = 31; b >= 0; --b) {
    unsigned Xt = X | (1u << b);
    int c = 0;
#pragma unroll
    for (int j = 0; j < 16; ++j) c += __popcll(__ballot(u[j] >= Xt));
    if (c >= 20) X = Xt;
  }
  const unsigned T = X;
  unsigned long long lanebit = 1ull << lane;
  int* op = idx + (size_t)row * 20;
  int base = 0;
#pragma unroll
  for (int j = 0; j < 16; ++j) {
    unsigned long long m = __ballot(u[j] > T);
    int before = __popcll(m & (lanebit - 1ull));
    if (m & lanebit) op[base + before] = j * 64 + lane;
    base += __popcll(m);
  }
#pragma unroll
  for (int j = 0; j < 16; ++j) {
    unsigned long long m = __ballot(u[j] == T);
    int before = __popcll(m & (lanebit - 1ull));
    int pos = base + before;
    if ((m & lanebit) && pos < 20) op[pos] = j * 64 + lane;
    base += __popcll(m);
  }
}

// ---------------- AB = F @ Wc^T : [16384, 2out] --------------------------------
__global__ __launch_bounds__(256) void ab_kernel(
    const float* __restrict__ F, int stride, int off, int dpad,
    const float* __restrict__ Wc, int twoout, float* __restrict__ AB) {
  int pb = blockIdx.x * 64, cb = blockIdx.y * 64;
  __shared__ __align__(16) float As[16][68];
  __shared__ __align__(16) float Bs[16][68];
  int tid = threadIdx.x;
  int tx = tid & 15, ty = tid >> 4;
  int lp = tid >> 2, lk = (tid & 3) * 4;
  float acc[4][4] = {};
  for (int k0 = 0; k0 < dpad; k0 += 16) {
    float4 av = *(const float4*)(F + (size_t)(pb + lp) * stride + off + k0 + lk);
    float4 bv = *(const float4*)(Wc + (size_t)(cb + lp) * dpad + k0 + lk);
    __syncthreads();
    As[lk + 0][lp] = av.x; As[lk + 1][lp] = av.y; As[lk + 2][lp] = av.z; As[lk + 3][lp] = av.w;
    Bs[lk + 0][lp] = bv.x; Bs[lk + 1][lp] = bv.y; Bs[lk + 2][lp] = bv.z; Bs[lk + 3][lp] = bv.w;
    __syncthreads();
#pragma unroll
    for (int kk = 0; kk < 16; ++kk) {
      float4 a4 = *(const float4*)&As[kk][ty * 4];
      float4 b4 = *(const float4*)&Bs[kk][tx * 4];
      float ar[4] = {a4.x, a4.y, a4.z, a4.w};
      float br[4] = {b4.x, b4.y, b4.z, b4.w};
#pragma unroll
      for (int i = 0; i < 4; ++i)
#pragma unroll
        for (int j = 0; j < 4; ++j) acc[i][j] = fmaf(ar[i], br[j], acc[i][j]);
    }
  }
#pragma unroll
  for (int i = 0; i < 4; ++i) {
    float4 o = {acc[i][0], acc[i][1], acc[i][2], acc[i][3]};
    *(float4*)(AB + (size_t)(pb + ty * 4 + i) * twoout + cb + tx * 4) = o;
  }
}

// ------- out[p,o] = max_t lrelu(A[idx[p][t],o] + Bc[p,o]); bf16 hi/lo too ----
__global__ void gathermax_kernel(const float* __restrict__ AB, const int* __restrict__ idx,
                                 float* __restrict__ catb,
                                 unsigned short* __restrict__ cat_hi,
                                 unsigned short* __restrict__ cat_lo,
                                 float* __restrict__ xx,
                                 int out, int catoff, int needxx) {
  int tid = threadIdx.x;
  int q = tid / out, o = tid - q * out;
  int ppb = 256 / out;
  int p = blockIdx.x * ppb + q;  // global point 0..16383
  int twoout = out * 2;
  const int* ip = idx + (size_t)p * 20;
  float bias = AB[(size_t)p * twoout + out + o];
  int bbase = p & ~1023;
  float m = -3.402823466e38f;
#pragma unroll
  for (int t = 0; t < 20; ++t) {
    int j = ip[t];
    float v = AB[(size_t)(bbase + j) * twoout + o] + bias;
    v = v > 0.f ? v : 0.2f * v;
    m = fmaxf(m, v);
  }
  size_t ci = (size_t)p * 512 + catoff + o;
  catb[ci] = m;
  unsigned short h = f2bf_rne(m);
  cat_hi[ci] = h;
  cat_lo[ci] = f2bf_rne(m - bf2f(h));
  if (needxx) {
    __shared__ float buf[256];
    buf[tid] = m * m;
    __syncthreads();
    for (int s = out >> 1; s > 0; s >>= 1) {
      if (o < s) buf[tid] += buf[tid + s];
      __syncthreads();
    }
    if (o == 0) xx[p] = buf[tid];
  }
}

// ------- partial[b,nb,o] = max over 64-pt chunk of lrelu(W4 @ cat), bf16x3 MFMA
__global__ __launch_bounds__(256) void gemmmax_kernel(
    const unsigned short* __restrict__ cat_hi, const unsigned short* __restrict__ cat_lo,
    const unsigned short* __restrict__ W4h, const unsigned short* __restrict__ W4l,
    float* __restrict__ partial) {
  int b = blockIdx.z;
  int ob = blockIdx.x * 128;        // o-tile base
  int ny = blockIdx.y;              // n-chunk (64 points)
  int p0 = b * 1024 + ny * 64;      // global point base
  __shared__ __align__(16) unsigned short Ah[128 * 40];
  __shared__ __align__(16) unsigned short Al[128 * 40];
  __shared__ __align__(16) unsigned short Bh[64 * 40];
  __shared__ __align__(16) unsigned short Bl[64 * 40];
  int tid = threadIdx.x;
  int wave = tid >> 6, lane = tid & 63;
  int l15 = lane & 15, l4 = lane >> 4;

  int arow = tid >> 1, ac0 = (tid & 1) * 2;
  int brow = tid >> 2, bc = tid & 3;

  f32x4 acc[2][4] = {};

  for (int k0 = 0; k0 < 512; k0 += 32) {
    uint4 a0 = *(const uint4*)(W4h + (size_t)(ob + arow) * 512 + k0 + ac0 * 8);
    uint4 a1 = *(const uint4*)(W4h + (size_t)(ob + arow) * 512 + k0 + (ac0 + 1) * 8);
    uint4 al0 = *(const uint4*)(W4l + (size_t)(ob + arow) * 512 + k0 + ac0 * 8);
    uint4 al1 = *(const uint4*)(W4l + (size_t)(ob + arow) * 512 + k0 + (ac0 + 1) * 8);
    uint4 b0 = *(const uint4*)(cat_hi + (size_t)(p0 + brow) * 512 + k0 + bc * 8);
    uint4 bl0 = *(const uint4*)(cat_lo + (size_t)(p0 + brow) * 512 + k0 + bc * 8);
    __syncthreads();
    *(uint4*)(Ah + arow * 40 + ac0 * 8) = a0;
    *(uint4*)(Ah + arow * 40 + (ac0 + 1) * 8) = a1;
    *(uint4*)(Al + arow * 40 + ac0 * 8) = al0;
    *(uint4*)(Al + arow * 40 + (ac0 + 1) * 8) = al1;
    *(uint4*)(Bh + brow * 40 + bc * 8) = b0;
    *(uint4*)(Bl + brow * 40 + bc * 8) = bl0;
    __syncthreads();

    bf16x8 ah[2], alr[2], bh[4], blr[4];
#pragma unroll
    for (int m = 0; m < 2; ++m) {
      int r = wave * 32 + m * 16 + l15;
      ah[m] = *(const bf16x8*)(Ah + r * 40 + l4 * 8);
      alr[m] = *(const bf16x8*)(Al + r * 40 + l4 * 8);
    }
#pragma unroll
    for (int n = 0; n < 4; ++n) {
      int r = n * 16 + l15;
      bh[n] = *(const bf16x8*)(Bh + r * 40 + l4 * 8);
      blr[n] = *(const bf16x8*)(Bl + r * 40 + l4 * 8);
    }
#pragma unroll
    for (int m = 0; m < 2; ++m)
#pragma unroll
      for (int n = 0; n < 4; ++n) {
        acc[m][n] = __builtin_amdgcn_mfma_f32_16x16x32_bf16(ah[m], bh[n], acc[m][n], 0, 0, 0);
        acc[m][n] = __builtin_amdgcn_mfma_f32_16x16x32_bf16(ah[m], blr[n], acc[m][n], 0, 0, 0);
        acc[m][n] = __builtin_amdgcn_mfma_f32_16x16x32_bf16(alr[m], bh[n], acc[m][n], 0, 0, 0);
      }
  }

#pragma unroll
  for (int m = 0; m < 2; ++m)
#pragma unroll
    for (int r = 0; r < 4; ++r) {
      float v = lrelu_f(acc[m][0][r]);
      v = fmaxf(v, lrelu_f(acc[m][1][r]));
      v = fmaxf(v, lrelu_f(acc[m][2][r]));
      v = fmaxf(v, lrelu_f(acc[m][3][r]));
      v = fmaxf(v, __shfl_xor(v, 1));
      v = fmaxf(v, __shfl_xor(v, 2));
      v = fmaxf(v, __shfl_xor(v, 4));
      v = fmaxf(v, __shfl_xor(v, 8));
      if (l15 == 0)
        partial[((size_t)(b * 16 + ny) << 10) + ob + wave * 32 + m * 16 + l4 * 4 + r] = v;
    }
}

// ---- zprep: z[b][1088] = [maxpool(partial) | y-MLP]; seed out[b] = L2b ------
__global__ __launch_bounds__(256) void zprep_kernel(
    const float* __restrict__ partial, const float* __restrict__ y,
    const float* __restrict__ F0w, const float* __restrict__ F0b,
    const float* __restrict__ F1w, const float* __restrict__ F1b,
    const float* __restrict__ L2b, float* __restrict__ zbuf,
    float* __restrict__ outp) {
  int b = blockIdx.x, tid = threadIdx.x;
  __shared__ float ye0[16];
  for (int o = tid; o < 1024; o += 256) {
    float m = -3.402823466e38f;
#pragma unroll
    for (int nb = 0; nb < 16; ++nb)
      m = fmaxf(m, partial[((size_t)(b * 16 + nb) << 10) + o]);
    zbuf[(size_t)b * 1088 + o] = m;
  }
  if (tid < 16) {
    float s = F0b[tid];
#pragma unroll
    for (int c = 0; c < 16; ++c) s = fmaf(y[b * 16 + c], F0w[tid * 16 + c], s);
    ye0[tid] = lrelu_f(s);
  }
  __syncthreads();
  if (tid < 64) {
    float s = F1b[tid];
#pragma unroll
    for (int c = 0; c < 16; ++c) s = fmaf(ye0[c], F1w[tid * 16 + c], s);
    zbuf[(size_t)b * 1088 + 1024 + tid] = lrelu_f(s);
  }
  if (tid == 0) outp[b] = L2b[0];
}

// ---- l0: z1[b][512] = lrelu(L0 @ z[b]); 4 threads per output row -----------
__global__ __launch_bounds__(256) void l0_kernel(
    const float* __restrict__ zbuf, const float* __restrict__ L0,
    float* __restrict__ z1buf) {
  int jt = blockIdx.x, b = blockIdx.y, tid = threadIdx.x;
  __shared__ __align__(16) float zs[1088];
  // 1088 floats = 272 float4; 256 threads cover 1024, tid<16 cover the tail.
  *(float4*)&zs[tid * 4] = *(const float4*)&zbuf[(size_t)b * 1088 + tid * 4];
  if (tid < 16)
    *(float4*)&zs[1024 + tid * 4] =
        *(const float4*)&zbuf[(size_t)b * 1088 + 1024 + tid * 4];
  __syncthreads();
  int j = jt * 64 + (tid >> 2), sl = tid & 3;
  const float4* Lr = (const float4*)(L0 + (size_t)j * 1088 + sl * 272);
  const float4* zr = (const float4*)(zs + sl * 272);
  float s = 0.f;
#pragma unroll 8
  for (int c = 0; c < 68; ++c) {
    float4 w = Lr[c], zz = zr[c];
    s = fmaf(w.x, zz.x, s); s = fmaf(w.y, zz.y, s);
    s = fmaf(w.z, zz.z, s); s = fmaf(w.w, zz.w, s);
  }
  s += __shfl_xor(s, 1);
  s += __shfl_xor(s, 2);
  if (sl == 0) z1buf[(size_t)b * 512 + j] = lrelu_f(s);
}

// ---- l1l2: z2 = lrelu(L1 @ z1); out[b] += sum z2*L2w (atomic per block) -----
__global__ __launch_bounds__(256) void l1l2_kernel(
    const float* __restrict__ z1buf, const float* __restrict__ L1,
    const float* __restrict__ L2w, float* __restrict__ outp) {
  int jt = blockIdx.x, b = blockIdx.y, tid = threadIdx.x;
  __shared__ __align__(16) float zs[512];
  if (tid < 128) *(float4*)&zs[tid * 4] = *(const float4*)&z1buf[(size_t)b * 512 + tid * 4];
  __syncthreads();
  int j = jt * 64 + (tid >> 2), sl = tid & 3;
  const float4* Lr = (const float4*)(L1 + (size_t)j * 512 + sl * 128);
  const float4* zr = (const float4*)(zs + sl * 128);
  float s = 0.f;
#pragma unroll 8
  for (int c = 0; c < 32; ++c) {
    float4 w = Lr[c], zz = zr[c];
    s = fmaf(w.x, zz.x, s); s = fmaf(w.y, zz.y, s);
    s = fmaf(w.z, zz.z, s); s = fmaf(w.w, zz.w, s);
  }
  s += __shfl_xor(s, 1);
  s += __shfl_xor(s, 2);
  float v = (sl == 0) ? lrelu_f(s) * L2w[j] : 0.f;
#pragma unroll
  for (int m = 1; m < 64; m <<= 1) v += __shfl_xor(v, m);
  __shared__ float wsum[4];
  if ((tid & 63) == 0) wsum[tid >> 6] = v;
  __syncthreads();
  if (tid == 0) atomicAdd(&outp[b], wsum[0] + wsum[1] + wsum[2] + wsum[3]);
}

extern "C" void kernel_launch(void* const* d_in, const int* in_sizes, int n_in,
                              void* d_out, int out_size, void* d_ws, size_t ws_size,
                              hipStream_t stream) {
  const float* x = (const float*)d_in[0];
  const float* y = (const float*)d_in[1];
  const float* Wl[4] = {(const float*)d_in[2], (const float*)d_in[3],
                        (const float*)d_in[4], (const float*)d_in[5]};
  const float* W4 = (const float*)d_in[6];
  const float* L0 = (const float*)d_in[7];
  const float* L1 = (const float*)d_in[8];
  const float* L2w = (const float*)d_in[9];
  const float* L2b = (const float*)d_in[10];
  const float* F0w = (const float*)d_in[11];
  const float* F0b = (const float*)d_in[12];
  const float* F1w = (const float*)d_in[13];
  const float* F1b = (const float*)d_in[14];

  float* ws = (float*)d_ws;
  float* xpad = ws;                     // 16384*16      = 262144
  float* catb = ws + 262144;            // 16384*512     = 8388608
  float* D    = ws + 8650752;           // 16*1024*1024  = 16777216
  float* AB   = ws + 25427968;          // 16384*512     = 8388608
  int*   idx  = (int*)(ws + 33816576);  // 16384*20      = 327680
  float* xx   = ws + 34144256;          // 16384
  float* Wc   = ws + 34160640;          // 512*128       = 65536
  float* part = ws + 34226176;          // 16*16*1024    = 262144
  unsigned short* cat_hi = (unsigned short*)(ws + 34488320);  // 16384*512 u16
  unsigned short* cat_lo = (unsigned short*)(ws + 38682624);  // 16384*512 u16
  unsigned short* W4h    = (unsigned short*)(ws + 42876928);  // 1024*512 u16
  unsigned short* W4l    = (unsigned short*)(ws + 43139072);  // 1024*512 u16
  float* zbuf  = ws + 43401216;         // 16*1088 = 17408
  float* z1buf = ws + 43418624;         // 16*512  = 8192

  prepx_kernel<<<64, 256, 0, stream>>>(x, xpad, xx);
  w4prep_kernel<<<2048, 256, 0, stream>>>(W4, W4h, W4l);

  struct LC { const float* F; int stride, off, d, dpad, out, catoff, needxx; };
  LC lc[4] = {
      {xpad, 16, 0, 6, 16, 64, 0, 1},
      {catb, 512, 0, 64, 64, 64, 64, 1},
      {catb, 512, 64, 64, 64, 128, 128, 1},
      {catb, 512, 128, 128, 128, 256, 256, 0},
  };
  for (int l = 0; l < 4; ++l) {
    LC c = lc[l];
    int twoout = c.out * 2;
    wcprep_kernel<<<(2 * c.out * c.dpad + 255) / 256, 256, 0, stream>>>(
        Wl[l], Wc, c.out, c.d, c.dpad);
    dist_kernel<<<dim3(16, 16, 16), 256, 0, stream>>>(c.F, xx, D, c.stride, c.off, c.dpad);
    topk_kernel<<<4096, 256, 0, stream>>>(D, idx);
    ab_kernel<<<dim3(256, twoout / 64), 256, 0, stream>>>(
        c.F, c.stride, c.off, c.dpad, Wc, twoout, AB);
    gathermax_kernel<<<16384 * c.out / 256, 256, 0, stream>>>(
        AB, idx, catb, cat_hi, cat_lo, xx, c.out, c.catoff, c.needxx);
  }
  gemmmax_kernel<<<dim3(8, 16, 16), 256, 0, stream>>>(cat_hi, cat_lo, W4h, W4l, part);
  zprep_kernel<<<16, 256, 0, stream>>>(part, y, F0w, F0b, F1w, F1b, L2b, zbuf,
                                       (float*)d_out);
  l0_kernel<<<dim3(8, 16), 256, 0, stream>>>(zbuf, L0, z1buf);
  l1l2_kernel<<<dim3(4, 16), 256, 0, stream>>>(z1buf, L1, L2w, (float*)d_out);
}